// Round 15
// baseline (355.238 us; speedup 1.0000x reference)
//
#include <hip/hip_runtime.h>
#include <math.h>

#define LN_EPS 1e-5f
#define TPB 512
#define ROWS_PER_TILE 128   // 8 waves x 16 rows per tile
#define TILES_PER_BLOCK 4   // grid-stride: each block does 4 tiles, stages weights once

typedef _Float16 half8 __attribute__((ext_vector_type(8)));
typedef float f32x4 __attribute__((ext_vector_type(4)));
typedef unsigned uint4v __attribute__((ext_vector_type(4)));

// fragment table offsets (halves); 512 halves (64 lanes x 8) per fragment.
#define OFF_W1   0        // 48 frags: towers k,v,r x cb(4) x kb(4), centered
#define OFF_WP   24576    // 4: residual param rows 128..130 (centered), K-slot j<3 @ g==0
#define OFF_QW1  26624    // 1: qW1 centered, K-slot j<3 @ g==0
#define OFF_KW2  27136    // 4: cb2(2) x kb(2), phi64-permuted K
#define OFF_VW2  29184    // 4
#define OFF_RW2  31232    // 4, centered
#define OFF_QW2  33280    // 2: cb2(2), phi16-padded K
#define OFF_AW1  34304    // 2: cb(2), phi32, centered
#define OFF_AW2  35328    // 1: phi32
#define OFF_RW3  35840    // 1: phi32
#define OFF_GW1  36352    // 1: phi32, centered
#define OFF_GW2  36864    // 1: phi16-padded
#define WL_HALVES 37376

__device__ _Float16 g_wfrag[WL_HALVES];   // 73 KB packed table (prepacked each launch)

__device__ __forceinline__ f32x4 mfma16(half8 a, half8 b, f32x4 c) {
  return __builtin_amdgcn_mfma_f32_16x16x32_f16(a, b, c, 0, 0, 0);
}
__device__ __forceinline__ unsigned pkrtz(float a, float b) {
  return __builtin_bit_cast(unsigned, __builtin_amdgcn_cvt_pkrtz(a, b));
}

// ---------------- prepack (byte-identical to validated R11/R14) ----------------

__device__ __forceinline__ void pack_l1(const float* __restrict__ W, int tower,
                                        int gtid, int gstride) {
  for (int idx = gtid; idx < 128 * 64; idx += gstride) {
    int k = idx >> 6, c = idx & 63;
    float m = 0.f;
    for (int c2 = 0; c2 < 64; ++c2) m += W[k * 64 + c2];
    float v = W[k * 64 + c] - m * (1.f / 64.f);
    int frag = tower * 16 + (c >> 4) * 4 + (k >> 5);
    int l = ((k >> 3) & 3) * 16 + (c & 15);
    g_wfrag[OFF_W1 + frag * 512 + l * 8 + (k & 7)] = (_Float16)v;
  }
}

__device__ __forceinline__ void pack_w2p(const float* __restrict__ W, int Kdim,
                                         int Ncols, int NB, int KB, int off,
                                         bool center, int gtid, int gstride) {
  int tot = NB * KB * 512;
  for (int idx = gtid; idx < tot; idx += gstride) {
    int j = idx & 7, l = (idx >> 3) & 63, frag = idx >> 9;
    int kb = frag % KB, cb2 = frag / KB;
    int g = l >> 4, lo = l & 15;
    int c2 = cb2 * 16 + lo;
    int ch = (kb * 2 + (j >> 2)) * 16 + g * 4 + (j & 3);
    float v = 0.f;
    if (c2 < Ncols && ch < Kdim) {
      v = W[ch * Ncols + c2];
      if (center) {
        float m = 0.f;
        for (int c = 0; c < Ncols; ++c) m += W[ch * Ncols + c];
        v -= m / (float)Ncols;
      }
    }
    g_wfrag[off + frag * 512 + l * 8 + j] = (_Float16)v;
  }
}

__device__ __forceinline__ void pack_pad16(const float* __restrict__ W, int Ncols,
                                           int NB, int off, int gtid, int gstride) {
  int tot = NB * 512;
  for (int idx = gtid; idx < tot; idx += gstride) {
    int j = idx & 7, l = (idx >> 3) & 63, cb2 = idx >> 9;
    int g = l >> 4, lo = l & 15;
    int c2 = cb2 * 16 + lo;
    float v = 0.f;
    if (j < 4 && c2 < Ncols) v = W[(g * 4 + j) * Ncols + c2];
    g_wfrag[off + cb2 * 512 + l * 8 + j] = (_Float16)v;
  }
}

__global__ void prepack_kernel(const float* kW1, const float* vW1, const float* rW1,
                               const float* kW2, const float* vW2, const float* rW2,
                               const float* qW1, const float* qW2, const float* aW1,
                               const float* aW2, const float* rW3, const float* gW1,
                               const float* gW2) {
  int gtid = blockIdx.x * blockDim.x + threadIdx.x;
  int gstride = gridDim.x * blockDim.x;
  pack_l1(kW1, 0, gtid, gstride);
  pack_l1(vW1, 1, gtid, gstride);
  pack_l1(rW1, 2, gtid, gstride);            // rows 0..127
  pack_w2p(kW2, 64, 32, 2, 2, OFF_KW2, false, gtid, gstride);
  pack_w2p(vW2, 64, 32, 2, 2, OFF_VW2, false, gtid, gstride);
  pack_w2p(rW2, 64, 32, 2, 2, OFF_RW2, true, gtid, gstride);
  pack_w2p(aW1, 32, 32, 2, 1, OFF_AW1, true, gtid, gstride);
  pack_w2p(aW2, 32, 16, 1, 1, OFF_AW2, false, gtid, gstride);
  pack_w2p(rW3, 32, 16, 1, 1, OFF_RW3, false, gtid, gstride);
  pack_w2p(gW1, 32, 16, 1, 1, OFF_GW1, true, gtid, gstride);
  pack_pad16(qW2, 32, 2, OFF_QW2, gtid, gstride);
  pack_pad16(gW2, 3, 1, OFF_GW2, gtid, gstride);
  // residual param frags: A[c = cb*16+lo, k=j (g==0, j<3)] = centered rW1 rows 128..130
  for (int idx = gtid; idx < 4 * 512; idx += gstride) {
    int j = idx & 7, l = (idx >> 3) & 63, cb = idx >> 9;
    int g = l >> 4, lo = l & 15;
    float v = 0.f;
    if (g == 0 && j < 3) {
      int k = 128 + j;
      float m = 0.f;
      for (int c = 0; c < 64; ++c) m += rW1[k * 64 + c];
      v = rW1[k * 64 + cb * 16 + lo] - m * (1.f / 64.f);
    }
    g_wfrag[OFF_WP + cb * 512 + l * 8 + j] = (_Float16)v;
  }
  // qW1 frag: A[c = lo, k=j (g==0, j<3)] = centered qW1
  for (int idx = gtid; idx < 512; idx += gstride) {
    int j = idx & 7, l = idx >> 3;
    int g = l >> 4, lo = l & 15;
    float v = 0.f;
    if (g == 0 && j < 3) {
      float m = 0.f;
      for (int c = 0; c < 16; ++c) m += qW1[j * 16 + c];
      v = qW1[j * 16 + lo] - m * (1.f / 16.f);
    }
    g_wfrag[OFF_QW1 + l * 8 + j] = (_Float16)v;
  }
}

// ------ main kernel: weights in LDS, reg-resident LN, 4-tile pipeline ------

__global__ __launch_bounds__(TPB, 4)
void approach_mfma_kernel(
    const float* __restrict__ rep, const float* __restrict__ par,
    const float* __restrict__ kg1, const float* __restrict__ kb1, const float* __restrict__ kb2,
    const float* __restrict__ qg1, const float* __restrict__ qb1, const float* __restrict__ qb2,
    const float* __restrict__ vg1, const float* __restrict__ vb1, const float* __restrict__ vb2,
    const float* __restrict__ ag1, const float* __restrict__ ab1, const float* __restrict__ ab2,
    const float* __restrict__ rg1, const float* __restrict__ rb1,
    const float* __restrict__ rg2, const float* __restrict__ rb2, const float* __restrict__ rb3,
    const float* __restrict__ gg1, const float* __restrict__ gb1, const float* __restrict__ gb2,
    float* __restrict__ out, int N)
{
  __shared__ __align__(16) _Float16 wl[WL_HALVES];   // 73 KB -> 2 blocks/CU

  const int tid = threadIdx.x;
  const int wave = tid >> 6, lane = tid & 63;
  const int lo = lane & 15;   // row index (B col / D col)
  const int g = lane >> 4;    // k-group / D-row group

  // ---- stage the fragment table (once per block)
  for (int i = tid * 8; i < WL_HALVES; i += TPB * 8)
    *reinterpret_cast<half8*>(&wl[i]) =
        *reinterpret_cast<const half8*>(&g_wfrag[i]);
  __syncthreads();

  auto ldf = [&](int off, int frag) -> half8 {
    return *reinterpret_cast<const half8*>(&wl[off + frag * 512 + lane * 8]);
  };
  const f32x4 z4 = {0.f, 0.f, 0.f, 0.f};

  const long long tile0 = (long long)blockIdx.x * TILES_PER_BLOCK;

  // ---- prefetch registers for the NEXT tile (raw f32), issue-early/consume-late
  f32x4 nx[8];
  float np0 = 0.f, np1 = 0.f, np2 = 0.f;

  // prologue: issue tile 0 loads
  {
    long long r = tile0 * ROWS_PER_TILE + wave * 16 + lo;
    if (r + 16 - lo <= N) {   // whole 16-row tile in range
      const float* xr = rep + (size_t)r * 128 + g * 8;
#pragma unroll
      for (int kb = 0; kb < 4; ++kb) {
        nx[2 * kb]     = *reinterpret_cast<const f32x4*>(xr + kb * 32);
        nx[2 * kb + 1] = *reinterpret_cast<const f32x4*>(xr + kb * 32 + 4);
      }
      const float* pr = par + (size_t)r * 3;
      np0 = pr[0]; np1 = pr[1]; np2 = pr[2];
    }
  }

#pragma unroll 1
  for (int it = 0; it < TILES_PER_BLOCK; ++it) {
    const long long row0 = (tile0 + it) * ROWS_PER_TILE + wave * 16;
    const bool active = (row0 + 16 <= N);

    // ---- convert prefetched raw -> MFMA B-fragments
    half8 xa[4], xp;
#pragma unroll
    for (int kb = 0; kb < 4; ++kb) {
      uint4v u;
      u[0] = pkrtz(nx[2 * kb][0], nx[2 * kb][1]);
      u[1] = pkrtz(nx[2 * kb][2], nx[2 * kb][3]);
      u[2] = pkrtz(nx[2 * kb + 1][0], nx[2 * kb + 1][1]);
      u[3] = pkrtz(nx[2 * kb + 1][2], nx[2 * kb + 1][3]);
      xa[kb] = __builtin_bit_cast(half8, u);
    }
    {
      unsigned w0 = pkrtz(np0, np1), w1 = pkrtz(np2, 0.f);
      uint4v u;
      u[0] = (g == 0) ? w0 : 0u; u[1] = (g == 0) ? w1 : 0u; u[2] = 0u; u[3] = 0u;
      xp = __builtin_bit_cast(half8, u);
    }

    // ---- issue NEXT tile's loads (latency hides under this tile's compute)
    if (it + 1 < TILES_PER_BLOCK) {
      long long r = (tile0 + it + 1) * ROWS_PER_TILE + wave * 16 + lo;
      if (r + 16 - lo <= N) {
        const float* xr = rep + (size_t)r * 128 + g * 8;
#pragma unroll
        for (int kb = 0; kb < 4; ++kb) {
          nx[2 * kb]     = *reinterpret_cast<const f32x4*>(xr + kb * 32);
          nx[2 * kb + 1] = *reinterpret_cast<const f32x4*>(xr + kb * 32 + 4);
        }
        const float* pr = par + (size_t)r * 3;
        np0 = pr[0]; np1 = pr[1]; np2 = pr[2];
      }
    }

    if (!active) continue;

    // ---- layer-1: h^T = W1^T x^T for k,v,r (+param tail) + q
    f32x4 aK[4], aV[4], aR[4];
#pragma unroll
    for (int cb = 0; cb < 4; ++cb) { aK[cb] = z4; aV[cb] = z4; aR[cb] = z4; }
#pragma unroll
    for (int cb = 0; cb < 4; ++cb)
#pragma unroll
      for (int kb = 0; kb < 4; ++kb) {
        aK[cb] = mfma16(ldf(OFF_W1, cb * 4 + kb), xa[kb], aK[cb]);
        aV[cb] = mfma16(ldf(OFF_W1, 16 + cb * 4 + kb), xa[kb], aV[cb]);
        aR[cb] = mfma16(ldf(OFF_W1, 32 + cb * 4 + kb), xa[kb], aR[cb]);
      }
#pragma unroll
    for (int cb = 0; cb < 4; ++cb) aR[cb] = mfma16(ldf(OFF_WP, cb), xp, aR[cb]);
    f32x4 aq = mfma16(ldf(OFF_QW1, 0), xp, z4);

    // LN64: mean-free rms-norm + affine + relu -> two phi64 B-frags
    auto ln64 = [&](const f32x4* a, const float* __restrict__ g1,
                    const float* __restrict__ b1, half8& b0, half8& b1o) {
      float t0 = 0.f, t1 = 0.f, t2 = 0.f, t3 = 0.f;
#pragma unroll
      for (int r = 0; r < 4; ++r) {
        t0 = fmaf(a[0][r], a[0][r], t0); t1 = fmaf(a[1][r], a[1][r], t1);
        t2 = fmaf(a[2][r], a[2][r], t2); t3 = fmaf(a[3][r], a[3][r], t3);
      }
      float ssq = (t0 + t1) + (t2 + t3);
      ssq += __shfl_xor(ssq, 16);
      ssq += __shfl_xor(ssq, 32);
      float rstd = rsqrtf(ssq * (1.f / 64.f) + LN_EPS);
      float h[4][4];
#pragma unroll
      for (int cb = 0; cb < 4; ++cb) {
        f32x4 gv = *reinterpret_cast<const f32x4*>(g1 + cb * 16 + g * 4);
        f32x4 bv = *reinterpret_cast<const f32x4*>(b1 + cb * 16 + g * 4);
#pragma unroll
        for (int r = 0; r < 4; ++r)
          h[cb][r] = fmaxf(fmaf(a[cb][r] * rstd, gv[r], bv[r]), 0.f);
      }
      uint4v u0, u1;
      u0[0] = pkrtz(h[0][0], h[0][1]); u0[1] = pkrtz(h[0][2], h[0][3]);
      u0[2] = pkrtz(h[1][0], h[1][1]); u0[3] = pkrtz(h[1][2], h[1][3]);
      u1[0] = pkrtz(h[2][0], h[2][1]); u1[1] = pkrtz(h[2][2], h[2][3]);
      u1[2] = pkrtz(h[3][0], h[3][1]); u1[3] = pkrtz(h[3][2], h[3][3]);
      b0 = __builtin_bit_cast(half8, u0);
      b1o = __builtin_bit_cast(half8, u1);
    };
    auto ln32 = [&](const f32x4* a, const float* __restrict__ g1,
                    const float* __restrict__ b1) -> half8 {
      float t0 = 0.f, t1 = 0.f;
#pragma unroll
      for (int r = 0; r < 4; ++r) {
        t0 = fmaf(a[0][r], a[0][r], t0); t1 = fmaf(a[1][r], a[1][r], t1);
      }
      float ssq = t0 + t1;
      ssq += __shfl_xor(ssq, 16);
      ssq += __shfl_xor(ssq, 32);
      float rstd = rsqrtf(ssq * (1.f / 32.f) + LN_EPS);
      float h[2][4];
#pragma unroll
      for (int cb = 0; cb < 2; ++cb) {
        f32x4 gv = *reinterpret_cast<const f32x4*>(g1 + cb * 16 + g * 4);
        f32x4 bv = *reinterpret_cast<const f32x4*>(b1 + cb * 16 + g * 4);
#pragma unroll
        for (int r = 0; r < 4; ++r)
          h[cb][r] = fmaxf(fmaf(a[cb][r] * rstd, gv[r], bv[r]), 0.f);
      }
      uint4v u;
      u[0] = pkrtz(h[0][0], h[0][1]); u[1] = pkrtz(h[0][2], h[0][3]);
      u[2] = pkrtz(h[1][0], h[1][1]); u[3] = pkrtz(h[1][2], h[1][3]);
      return __builtin_bit_cast(half8, u);
    };
    auto ln16 = [&](f32x4 a, const float* __restrict__ g1,
                    const float* __restrict__ b1) -> half8 {
      float ssq = 0.f;
#pragma unroll
      for (int r = 0; r < 4; ++r) ssq = fmaf(a[r], a[r], ssq);
      ssq += __shfl_xor(ssq, 16);
      ssq += __shfl_xor(ssq, 32);
      float rstd = rsqrtf(ssq * (1.f / 16.f) + LN_EPS);
      f32x4 gv = *reinterpret_cast<const f32x4*>(g1 + g * 4);
      f32x4 bv = *reinterpret_cast<const f32x4*>(b1 + g * 4);
      float h[4];
#pragma unroll
      for (int r = 0; r < 4; ++r)
        h[r] = fmaxf(fmaf(a[r] * rstd, gv[r], bv[r]), 0.f);
      uint4v u;
      u[0] = pkrtz(h[0], h[1]); u[1] = pkrtz(h[2], h[3]); u[2] = 0u; u[3] = 0u;
      return __builtin_bit_cast(half8, u);
    };

    f32x4 kk[2], vv[2], qq[2], r16v, a16v;
    // ---- key tower layer-2
    {
      half8 b0, b1;
      ln64(aK, kg1, kb1, b0, b1);
#pragma unroll
      for (int cb2 = 0; cb2 < 2; ++cb2) {
        f32x4 o = mfma16(ldf(OFF_KW2, cb2 * 2 + 1), b1,
                         mfma16(ldf(OFF_KW2, cb2 * 2), b0, z4));
        f32x4 bb = *reinterpret_cast<const f32x4*>(kb2 + cb2 * 16 + g * 4);
#pragma unroll
        for (int r = 0; r < 4; ++r) o[r] += bb[r];
        kk[cb2] = o;
      }
    }
    // ---- value tower layer-2
    {
      half8 b0, b1;
      ln64(aV, vg1, vb1, b0, b1);
#pragma unroll
      for (int cb2 = 0; cb2 < 2; ++cb2) {
        f32x4 o = mfma16(ldf(OFF_VW2, cb2 * 2 + 1), b1,
                         mfma16(ldf(OFF_VW2, cb2 * 2), b0, z4));
        f32x4 bb = *reinterpret_cast<const f32x4*>(vb2 + cb2 * 16 + g * 4);
#pragma unroll
        for (int r = 0; r < 4; ++r) o[r] += bb[r];
        vv[cb2] = o;
      }
    }
    // ---- residual tower layers 2-3
    {
      half8 b0, b1;
      ln64(aR, rg1, rb1, b0, b1);
      f32x4 r32[2];
#pragma unroll
      for (int cb = 0; cb < 2; ++cb)
        r32[cb] = mfma16(ldf(OFF_RW2, cb * 2 + 1), b1,
                         mfma16(ldf(OFF_RW2, cb * 2), b0, z4));
      half8 b32 = ln32(r32, rg2, rb2);
      f32x4 o = mfma16(ldf(OFF_RW3, 0), b32, z4);
      f32x4 bb = *reinterpret_cast<const f32x4*>(rb3 + g * 4);
#pragma unroll
      for (int r = 0; r < 4; ++r) o[r] += bb[r];
      r16v = o;
    }
    // ---- query tower layer-2
    {
      half8 bq = ln16(aq, qg1, qb1);
#pragma unroll
      for (int cb2 = 0; cb2 < 2; ++cb2) {
        f32x4 o = mfma16(ldf(OFF_QW2, cb2), bq, z4);
        f32x4 bb = *reinterpret_cast<const f32x4*>(qb2 + cb2 * 16 + g * 4);
#pragma unroll
        for (int r = 0; r < 4; ++r) o[r] += bb[r];
        qq[cb2] = o;
      }
    }
    // ---- attention: softmax(q*k)*v (raw exp; proven R8-R14)
    {
      float e[2][4];
      float s0 = 0.f, s1 = 0.f;
#pragma unroll
      for (int r = 0; r < 4; ++r) {
        e[0][r] = __expf(qq[0][r] * kk[0][r]);
        e[1][r] = __expf(qq[1][r] * kk[1][r]);
        s0 += e[0][r]; s1 += e[1][r];
      }
      float sm = s0 + s1;
      sm += __shfl_xor(sm, 16);
      sm += __shfl_xor(sm, 32);
      float inv = 1.f / sm;
      float at[2][4];
#pragma unroll
      for (int cb = 0; cb < 2; ++cb)
#pragma unroll
        for (int r = 0; r < 4; ++r) at[cb][r] = e[cb][r] * inv * vv[cb][r];
      uint4v ua;
      ua[0] = pkrtz(at[0][0], at[0][1]); ua[1] = pkrtz(at[0][2], at[0][3]);
      ua[2] = pkrtz(at[1][0], at[1][1]); ua[3] = pkrtz(at[1][2], at[1][3]);
      half8 ba = __builtin_bit_cast(half8, ua);
      f32x4 h32[2];
#pragma unroll
      for (int cb = 0; cb < 2; ++cb) h32[cb] = mfma16(ldf(OFF_AW1, cb), ba, z4);
      half8 bh = ln32(h32, ag1, ab1);
      f32x4 o = mfma16(ldf(OFF_AW2, 0), bh, z4);
      f32x4 bb = *reinterpret_cast<const f32x4*>(ab2 + g * 4);
#pragma unroll
      for (int r = 0; r < 4; ++r) o[r] += bb[r];
      a16v = o;
    }
    // ---- get_approach tower: concat(att [j<4], res [j>=4]) -> gW1 -> LN -> gW2
    {
      uint4v uf;
      uf[0] = pkrtz(a16v[0], a16v[1]); uf[1] = pkrtz(a16v[2], a16v[3]);
      uf[2] = pkrtz(r16v[0], r16v[1]); uf[3] = pkrtz(r16v[2], r16v[3]);
      half8 bf = __builtin_bit_cast(half8, uf);
      f32x4 f1 = mfma16(ldf(OFF_GW1, 0), bf, z4);
      half8 bf1 = ln16(f1, gg1, gb1);
      f32x4 og = mfma16(ldf(OFF_GW2, 0), bf1, z4);
      if (g == 0) {
        float* op = out + (size_t)(row0 + lo) * 3;
#pragma unroll
        for (int r = 0; r < 3; ++r) op[r] = og[r] + gb2[r];
      }
    }
  }
}

// ---------------- launch ----------------

extern "C" void kernel_launch(void* const* d_in, const int* in_sizes, int n_in,
                              void* d_out, int out_size, void* d_ws, size_t ws_size,
                              hipStream_t stream) {
  const float* rep = (const float*)d_in[0];
  const float* par = (const float*)d_in[1];
  const float* kW1 = (const float*)d_in[2];
  const float* kg1 = (const float*)d_in[3];
  const float* kb1 = (const float*)d_in[4];
  const float* kW2 = (const float*)d_in[5];
  const float* kb2 = (const float*)d_in[6];
  const float* qW1 = (const float*)d_in[7];
  const float* qg1 = (const float*)d_in[8];
  const float* qb1 = (const float*)d_in[9];
  const float* qW2 = (const float*)d_in[10];
  const float* qb2 = (const float*)d_in[11];
  const float* vW1 = (const float*)d_in[12];
  const float* vg1 = (const float*)d_in[13];
  const float* vb1 = (const float*)d_in[14];
  const float* vW2 = (const float*)d_in[15];
  const float* vb2 = (const float*)d_in[16];
  const float* aW1 = (const float*)d_in[17];
  const float* ag1 = (const float*)d_in[18];
  const float* ab1 = (const float*)d_in[19];
  const float* aW2 = (const float*)d_in[20];
  const float* ab2 = (const float*)d_in[21];
  const float* rW1 = (const float*)d_in[22];
  const float* rg1 = (const float*)d_in[23];
  const float* rb1 = (const float*)d_in[24];
  const float* rW2 = (const float*)d_in[25];
  const float* rg2 = (const float*)d_in[26];
  const float* rb2 = (const float*)d_in[27];
  const float* rW3 = (const float*)d_in[28];
  const float* rb3 = (const float*)d_in[29];
  const float* gW1 = (const float*)d_in[30];
  const float* gg1 = (const float*)d_in[31];
  const float* gb1 = (const float*)d_in[32];
  const float* gW2 = (const float*)d_in[33];
  const float* gb2 = (const float*)d_in[34];

  const int N = in_sizes[0] / 128;
  float* out = (float*)d_out;

  prepack_kernel<<<40, 256, 0, stream>>>(kW1, vW1, rW1, kW2, vW2, rW2,
                                         qW1, qW2, aW1, aW2, rW3, gW1, gW2);

  const int rows_per_block = ROWS_PER_TILE * TILES_PER_BLOCK;
  const int grid = (N + rows_per_block - 1) / rows_per_block;
  approach_mfma_kernel<<<grid, TPB, 0, stream>>>(
      rep, par,
      kg1, kb1, kb2,
      qg1, qb1, qb2,
      vg1, vb1, vb2,
      ag1, ab1, ab2,
      rg1, rb1, rg2, rb2, rb3,
      gg1, gb1, gb2,
      out, N);
}

// Round 16
// 257.496 us; speedup vs baseline: 1.3796x; 1.3796x over previous
//
#include <hip/hip_runtime.h>
#include <math.h>

#define LN_EPS 1e-5f
#define TPB 512
#define ROWS_PER_BLOCK 128  // 8 waves x 16 rows; layer-1 weights staged in LDS

typedef _Float16 half8 __attribute__((ext_vector_type(8)));
typedef float f32x4 __attribute__((ext_vector_type(4)));
typedef unsigned uint4v __attribute__((ext_vector_type(4)));

// fragment table offsets (halves); 512 halves (64 lanes x 8) per fragment.
#define OFF_W1   0        // 48 frags: towers k,v,r x cb(4) x kb(4), centered
#define OFF_WP   24576    // 4: residual param rows (centered), K-slot j<3 @ g==0
#define OFF_QW1  26624    // 1: qW1 centered
#define LDS_HALVES 27136  // W1+WP+QW1 staged in LDS: 53 KB -> 3 blocks/CU
#define OFF_KW2  27136    // 4: cb2(2) x kb(2), phi64-permuted K   (L2-resident)
#define OFF_VW2  29184    // 4
#define OFF_RW2  31232    // 4, centered
#define OFF_QW2  33280    // 2: cb2(2), phi16-padded K
#define OFF_AW1  34304    // 2: cb(2), phi32, centered
#define OFF_AW2  35328    // 1: phi32
#define OFF_RW3  35840    // 1: phi32
#define OFF_GW1  36352    // 1: phi32, centered
#define OFF_GW2  36864    // 1: phi16-padded
#define WL_HALVES 37376

__device__ _Float16 g_wfrag[WL_HALVES];   // 73 KB packed table (prepacked each launch)

__device__ __forceinline__ f32x4 mfma16(half8 a, half8 b, f32x4 c) {
  return __builtin_amdgcn_mfma_f32_16x16x32_f16(a, b, c, 0, 0, 0);
}
__device__ __forceinline__ unsigned pkrtz(float a, float b) {
  return __builtin_bit_cast(unsigned, __builtin_amdgcn_cvt_pkrtz(a, b));
}

// ---------------- prepack (byte-identical to validated R11/R14) ----------------

__device__ __forceinline__ void pack_l1(const float* __restrict__ W, int tower,
                                        int gtid, int gstride) {
  for (int idx = gtid; idx < 128 * 64; idx += gstride) {
    int k = idx >> 6, c = idx & 63;
    float m = 0.f;
    for (int c2 = 0; c2 < 64; ++c2) m += W[k * 64 + c2];
    float v = W[k * 64 + c] - m * (1.f / 64.f);
    int frag = tower * 16 + (c >> 4) * 4 + (k >> 5);
    int l = ((k >> 3) & 3) * 16 + (c & 15);
    g_wfrag[OFF_W1 + frag * 512 + l * 8 + (k & 7)] = (_Float16)v;
  }
}

__device__ __forceinline__ void pack_w2p(const float* __restrict__ W, int Kdim,
                                         int Ncols, int NB, int KB, int off,
                                         bool center, int gtid, int gstride) {
  int tot = NB * KB * 512;
  for (int idx = gtid; idx < tot; idx += gstride) {
    int j = idx & 7, l = (idx >> 3) & 63, frag = idx >> 9;
    int kb = frag % KB, cb2 = frag / KB;
    int g = l >> 4, lo = l & 15;
    int c2 = cb2 * 16 + lo;
    int ch = (kb * 2 + (j >> 2)) * 16 + g * 4 + (j & 3);
    float v = 0.f;
    if (c2 < Ncols && ch < Kdim) {
      v = W[ch * Ncols + c2];
      if (center) {
        float m = 0.f;
        for (int c = 0; c < Ncols; ++c) m += W[ch * Ncols + c];
        v -= m / (float)Ncols;
      }
    }
    g_wfrag[off + frag * 512 + l * 8 + j] = (_Float16)v;
  }
}

__device__ __forceinline__ void pack_pad16(const float* __restrict__ W, int Ncols,
                                           int NB, int off, int gtid, int gstride) {
  int tot = NB * 512;
  for (int idx = gtid; idx < tot; idx += gstride) {
    int j = idx & 7, l = (idx >> 3) & 63, cb2 = idx >> 9;
    int g = l >> 4, lo = l & 15;
    int c2 = cb2 * 16 + lo;
    float v = 0.f;
    if (j < 4 && c2 < Ncols) v = W[(g * 4 + j) * Ncols + c2];
    g_wfrag[off + cb2 * 512 + l * 8 + j] = (_Float16)v;
  }
}

__global__ void prepack_kernel(const float* kW1, const float* vW1, const float* rW1,
                               const float* kW2, const float* vW2, const float* rW2,
                               const float* qW1, const float* qW2, const float* aW1,
                               const float* aW2, const float* rW3, const float* gW1,
                               const float* gW2) {
  int gtid = blockIdx.x * blockDim.x + threadIdx.x;
  int gstride = gridDim.x * blockDim.x;
  pack_l1(kW1, 0, gtid, gstride);
  pack_l1(vW1, 1, gtid, gstride);
  pack_l1(rW1, 2, gtid, gstride);            // rows 0..127
  pack_w2p(kW2, 64, 32, 2, 2, OFF_KW2, false, gtid, gstride);
  pack_w2p(vW2, 64, 32, 2, 2, OFF_VW2, false, gtid, gstride);
  pack_w2p(rW2, 64, 32, 2, 2, OFF_RW2, true, gtid, gstride);
  pack_w2p(aW1, 32, 32, 2, 1, OFF_AW1, true, gtid, gstride);
  pack_w2p(aW2, 32, 16, 1, 1, OFF_AW2, false, gtid, gstride);
  pack_w2p(rW3, 32, 16, 1, 1, OFF_RW3, false, gtid, gstride);
  pack_w2p(gW1, 32, 16, 1, 1, OFF_GW1, true, gtid, gstride);
  pack_pad16(qW2, 32, 2, OFF_QW2, gtid, gstride);
  pack_pad16(gW2, 3, 1, OFF_GW2, gtid, gstride);
  // residual param frags: A[c = cb*16+lo, k=j (g==0, j<3)] = centered rW1 rows 128..130
  for (int idx = gtid; idx < 4 * 512; idx += gstride) {
    int j = idx & 7, l = (idx >> 3) & 63, cb = idx >> 9;
    int g = l >> 4, lo = l & 15;
    float v = 0.f;
    if (g == 0 && j < 3) {
      int k = 128 + j;
      float m = 0.f;
      for (int c = 0; c < 64; ++c) m += rW1[k * 64 + c];
      v = rW1[k * 64 + cb * 16 + lo] - m * (1.f / 64.f);
    }
    g_wfrag[OFF_WP + cb * 512 + l * 8 + j] = (_Float16)v;
  }
  // qW1 frag: A[c = lo, k=j (g==0, j<3)] = centered qW1
  for (int idx = gtid; idx < 512; idx += gstride) {
    int j = idx & 7, l = idx >> 3;
    int g = l >> 4, lo = l & 15;
    float v = 0.f;
    if (g == 0 && j < 3) {
      float m = 0.f;
      for (int c = 0; c < 16; ++c) m += qW1[j * 16 + c];
      v = qW1[j * 16 + lo] - m * (1.f / 16.f);
    }
    g_wfrag[OFF_QW1 + l * 8 + j] = (_Float16)v;
  }
}

// ------ main kernel: layer-1 weights in LDS (3 blocks/CU), layer-2+ from L2 ------

__global__ __launch_bounds__(TPB, 6)
void approach_mfma_kernel(
    const float* __restrict__ rep, const float* __restrict__ par,
    const float* __restrict__ kg1, const float* __restrict__ kb1, const float* __restrict__ kb2,
    const float* __restrict__ qg1, const float* __restrict__ qb1, const float* __restrict__ qb2,
    const float* __restrict__ vg1, const float* __restrict__ vb1, const float* __restrict__ vb2,
    const float* __restrict__ ag1, const float* __restrict__ ab1, const float* __restrict__ ab2,
    const float* __restrict__ rg1, const float* __restrict__ rb1,
    const float* __restrict__ rg2, const float* __restrict__ rb2, const float* __restrict__ rb3,
    const float* __restrict__ gg1, const float* __restrict__ gb1, const float* __restrict__ gb2,
    float* __restrict__ out, int N)
{
  __shared__ __align__(16) _Float16 wl[LDS_HALVES];   // 53 KB -> 3 blocks/CU

  const int tid = threadIdx.x;
  const int wave = tid >> 6, lane = tid & 63;
  const int lo = lane & 15;   // row index (B col / D col)
  const int g = lane >> 4;    // k-group / D-row group
  const long long row0 = (long long)blockIdx.x * ROWS_PER_BLOCK + wave * 16;

  // ---- stage the layer-1 fragment table (once per block)
  for (int i = tid * 8; i < LDS_HALVES; i += TPB * 8)
    *reinterpret_cast<half8*>(&wl[i]) =
        *reinterpret_cast<const half8*>(&g_wfrag[i]);
  __syncthreads();

  if (row0 + 16 > N) return;

  auto ldf = [&](int off, int frag) -> half8 {   // LDS (layer-1 tables)
    return *reinterpret_cast<const half8*>(&wl[off + frag * 512 + lane * 8]);
  };
  auto ldg = [&](int off, int frag) -> half8 {   // global/L2 (layer-2+ tables)
    return *reinterpret_cast<const half8*>(&g_wfrag[off + frag * 512 + lane * 8]);
  };
  const f32x4 z4 = {0.f, 0.f, 0.f, 0.f};

  // ---- B = x^T fragments: lane supplies x[row=lo, k = kb*32 + g*8 + j]
  half8 xa[4];
  {
    const float* xr = rep + (size_t)(row0 + lo) * 128 + g * 8;
#pragma unroll
    for (int kb = 0; kb < 4; ++kb) {
      f32x4 u0 = *reinterpret_cast<const f32x4*>(xr + kb * 32);
      f32x4 u1 = *reinterpret_cast<const f32x4*>(xr + kb * 32 + 4);
      uint4v u;
      u[0] = pkrtz(u0[0], u0[1]); u[1] = pkrtz(u0[2], u0[3]);
      u[2] = pkrtz(u1[0], u1[1]); u[3] = pkrtz(u1[2], u1[3]);
      xa[kb] = __builtin_bit_cast(half8, u);
    }
  }
  // ---- B = params fragment (k-slots j<3 at g==0)
  half8 xp;
  {
    const float* pr = par + (size_t)(row0 + lo) * 3;
    unsigned w0 = pkrtz(pr[0], pr[1]), w1 = pkrtz(pr[2], 0.f);
    uint4v u;
    u[0] = (g == 0) ? w0 : 0u; u[1] = (g == 0) ? w1 : 0u; u[2] = 0u; u[3] = 0u;
    xp = __builtin_bit_cast(half8, u);
  }

  // ---- layer-1: h^T = W1^T x^T for k,v,r (+param tail) + q  (all from LDS)
  f32x4 aK[4], aV[4], aR[4];
#pragma unroll
  for (int cb = 0; cb < 4; ++cb) { aK[cb] = z4; aV[cb] = z4; aR[cb] = z4; }
#pragma unroll
  for (int cb = 0; cb < 4; ++cb)
#pragma unroll
    for (int kb = 0; kb < 4; ++kb) {
      aK[cb] = mfma16(ldf(OFF_W1, cb * 4 + kb), xa[kb], aK[cb]);
      aV[cb] = mfma16(ldf(OFF_W1, 16 + cb * 4 + kb), xa[kb], aV[cb]);
      aR[cb] = mfma16(ldf(OFF_W1, 32 + cb * 4 + kb), xa[kb], aR[cb]);
    }
#pragma unroll
  for (int cb = 0; cb < 4; ++cb) aR[cb] = mfma16(ldf(OFF_WP, cb), xp, aR[cb]);
  f32x4 aq = mfma16(ldf(OFF_QW1, 0), xp, z4);

  // LN64: mean-free rms-norm + affine + relu -> two phi64 B-frags
  auto ln64 = [&](const f32x4* a, const float* __restrict__ g1,
                  const float* __restrict__ b1, half8& b0, half8& b1o) {
    float t0 = 0.f, t1 = 0.f, t2 = 0.f, t3 = 0.f;
#pragma unroll
    for (int r = 0; r < 4; ++r) {
      t0 = fmaf(a[0][r], a[0][r], t0); t1 = fmaf(a[1][r], a[1][r], t1);
      t2 = fmaf(a[2][r], a[2][r], t2); t3 = fmaf(a[3][r], a[3][r], t3);
    }
    float ssq = (t0 + t1) + (t2 + t3);
    ssq += __shfl_xor(ssq, 16);
    ssq += __shfl_xor(ssq, 32);
    float rstd = rsqrtf(ssq * (1.f / 64.f) + LN_EPS);
    float h[4][4];
#pragma unroll
    for (int cb = 0; cb < 4; ++cb) {
      f32x4 gv = *reinterpret_cast<const f32x4*>(g1 + cb * 16 + g * 4);
      f32x4 bv = *reinterpret_cast<const f32x4*>(b1 + cb * 16 + g * 4);
#pragma unroll
      for (int r = 0; r < 4; ++r)
        h[cb][r] = fmaxf(fmaf(a[cb][r] * rstd, gv[r], bv[r]), 0.f);
    }
    uint4v u0, u1;
    u0[0] = pkrtz(h[0][0], h[0][1]); u0[1] = pkrtz(h[0][2], h[0][3]);
    u0[2] = pkrtz(h[1][0], h[1][1]); u0[3] = pkrtz(h[1][2], h[1][3]);
    u1[0] = pkrtz(h[2][0], h[2][1]); u1[1] = pkrtz(h[2][2], h[2][3]);
    u1[2] = pkrtz(h[3][0], h[3][1]); u1[3] = pkrtz(h[3][2], h[3][3]);
    b0 = __builtin_bit_cast(half8, u0);
    b1o = __builtin_bit_cast(half8, u1);
  };
  auto ln32 = [&](const f32x4* a, const float* __restrict__ g1,
                  const float* __restrict__ b1) -> half8 {
    float t0 = 0.f, t1 = 0.f;
#pragma unroll
    for (int r = 0; r < 4; ++r) {
      t0 = fmaf(a[0][r], a[0][r], t0); t1 = fmaf(a[1][r], a[1][r], t1);
    }
    float ssq = t0 + t1;
    ssq += __shfl_xor(ssq, 16);
    ssq += __shfl_xor(ssq, 32);
    float rstd = rsqrtf(ssq * (1.f / 32.f) + LN_EPS);
    float h[2][4];
#pragma unroll
    for (int cb = 0; cb < 2; ++cb) {
      f32x4 gv = *reinterpret_cast<const f32x4*>(g1 + cb * 16 + g * 4);
      f32x4 bv = *reinterpret_cast<const f32x4*>(b1 + cb * 16 + g * 4);
#pragma unroll
      for (int r = 0; r < 4; ++r)
        h[cb][r] = fmaxf(fmaf(a[cb][r] * rstd, gv[r], bv[r]), 0.f);
    }
    uint4v u;
    u[0] = pkrtz(h[0][0], h[0][1]); u[1] = pkrtz(h[0][2], h[0][3]);
    u[2] = pkrtz(h[1][0], h[1][1]); u[3] = pkrtz(h[1][2], h[1][3]);
    return __builtin_bit_cast(half8, u);
  };
  auto ln16 = [&](f32x4 a, const float* __restrict__ g1,
                  const float* __restrict__ b1) -> half8 {
    float ssq = 0.f;
#pragma unroll
    for (int r = 0; r < 4; ++r) ssq = fmaf(a[r], a[r], ssq);
    ssq += __shfl_xor(ssq, 16);
    ssq += __shfl_xor(ssq, 32);
    float rstd = rsqrtf(ssq * (1.f / 16.f) + LN_EPS);
    f32x4 gv = *reinterpret_cast<const f32x4*>(g1 + g * 4);
    f32x4 bv = *reinterpret_cast<const f32x4*>(b1 + g * 4);
    float h[4];
#pragma unroll
    for (int r = 0; r < 4; ++r)
      h[r] = fmaxf(fmaf(a[r] * rstd, gv[r], bv[r]), 0.f);
    uint4v u;
    u[0] = pkrtz(h[0], h[1]); u[1] = pkrtz(h[2], h[3]); u[2] = 0u; u[3] = 0u;
    return __builtin_bit_cast(half8, u);
  };

  // ---- key tower layer-2 (weights from L2)
  f32x4 kk[2], vv[2], qq[2], r16v, a16v;
  {
    half8 b0, b1;
    ln64(aK, kg1, kb1, b0, b1);
#pragma unroll
    for (int cb2 = 0; cb2 < 2; ++cb2) {
      f32x4 o = mfma16(ldg(OFF_KW2, cb2 * 2 + 1), b1,
                       mfma16(ldg(OFF_KW2, cb2 * 2), b0, z4));
      f32x4 bb = *reinterpret_cast<const f32x4*>(kb2 + cb2 * 16 + g * 4);
#pragma unroll
      for (int r = 0; r < 4; ++r) o[r] += bb[r];
      kk[cb2] = o;
    }
  }
  // ---- value tower layer-2
  {
    half8 b0, b1;
    ln64(aV, vg1, vb1, b0, b1);
#pragma unroll
    for (int cb2 = 0; cb2 < 2; ++cb2) {
      f32x4 o = mfma16(ldg(OFF_VW2, cb2 * 2 + 1), b1,
                       mfma16(ldg(OFF_VW2, cb2 * 2), b0, z4));
      f32x4 bb = *reinterpret_cast<const f32x4*>(vb2 + cb2 * 16 + g * 4);
#pragma unroll
      for (int r = 0; r < 4; ++r) o[r] += bb[r];
      vv[cb2] = o;
    }
  }
  // ---- residual tower layers 2-3
  {
    half8 b0, b1;
    ln64(aR, rg1, rb1, b0, b1);
    f32x4 r32[2];
#pragma unroll
    for (int cb = 0; cb < 2; ++cb)
      r32[cb] = mfma16(ldg(OFF_RW2, cb * 2 + 1), b1,
                       mfma16(ldg(OFF_RW2, cb * 2), b0, z4));
    half8 b32 = ln32(r32, rg2, rb2);
    f32x4 o = mfma16(ldg(OFF_RW3, 0), b32, z4);
    f32x4 bb = *reinterpret_cast<const f32x4*>(rb3 + g * 4);
#pragma unroll
    for (int r = 0; r < 4; ++r) o[r] += bb[r];
    r16v = o;
  }
  // ---- query tower layer-2
  {
    half8 bq = ln16(aq, qg1, qb1);
#pragma unroll
    for (int cb2 = 0; cb2 < 2; ++cb2) {
      f32x4 o = mfma16(ldg(OFF_QW2, cb2), bq, z4);
      f32x4 bb = *reinterpret_cast<const f32x4*>(qb2 + cb2 * 16 + g * 4);
#pragma unroll
      for (int r = 0; r < 4; ++r) o[r] += bb[r];
      qq[cb2] = o;
    }
  }
  // ---- attention: softmax(q*k)*v (raw exp; proven R8-R15)
  {
    float e[2][4];
    float s0 = 0.f, s1 = 0.f;
#pragma unroll
    for (int r = 0; r < 4; ++r) {
      e[0][r] = __expf(qq[0][r] * kk[0][r]);
      e[1][r] = __expf(qq[1][r] * kk[1][r]);
      s0 += e[0][r]; s1 += e[1][r];
    }
    float sm = s0 + s1;
    sm += __shfl_xor(sm, 16);
    sm += __shfl_xor(sm, 32);
    float inv = 1.f / sm;
    float at[2][4];
#pragma unroll
    for (int cb = 0; cb < 2; ++cb)
#pragma unroll
      for (int r = 0; r < 4; ++r) at[cb][r] = e[cb][r] * inv * vv[cb][r];
    uint4v ua;
    ua[0] = pkrtz(at[0][0], at[0][1]); ua[1] = pkrtz(at[0][2], at[0][3]);
    ua[2] = pkrtz(at[1][0], at[1][1]); ua[3] = pkrtz(at[1][2], at[1][3]);
    half8 ba = __builtin_bit_cast(half8, ua);
    f32x4 h32[2];
#pragma unroll
    for (int cb = 0; cb < 2; ++cb) h32[cb] = mfma16(ldg(OFF_AW1, cb), ba, z4);
    half8 bh = ln32(h32, ag1, ab1);
    f32x4 o = mfma16(ldg(OFF_AW2, 0), bh, z4);
    f32x4 bb = *reinterpret_cast<const f32x4*>(ab2 + g * 4);
#pragma unroll
    for (int r = 0; r < 4; ++r) o[r] += bb[r];
    a16v = o;
  }
  // ---- get_approach tower: concat(att [j<4], res [j>=4]) -> gW1 -> LN -> gW2
  {
    uint4v uf;
    uf[0] = pkrtz(a16v[0], a16v[1]); uf[1] = pkrtz(a16v[2], a16v[3]);
    uf[2] = pkrtz(r16v[0], r16v[1]); uf[3] = pkrtz(r16v[2], r16v[3]);
    half8 bf = __builtin_bit_cast(half8, uf);
    f32x4 f1 = mfma16(ldg(OFF_GW1, 0), bf, z4);
    half8 bf1 = ln16(f1, gg1, gb1);
    f32x4 og = mfma16(ldg(OFF_GW2, 0), bf1, z4);
    if (g == 0) {
      float* op = out + (size_t)(row0 + lo) * 3;
#pragma unroll
      for (int r = 0; r < 3; ++r) op[r] = og[r] + gb2[r];
    }
  }
}

// ---------------- launch ----------------

extern "C" void kernel_launch(void* const* d_in, const int* in_sizes, int n_in,
                              void* d_out, int out_size, void* d_ws, size_t ws_size,
                              hipStream_t stream) {
  const float* rep = (const float*)d_in[0];
  const float* par = (const float*)d_in[1];
  const float* kW1 = (const float*)d_in[2];
  const float* kg1 = (const float*)d_in[3];
  const float* kb1 = (const float*)d_in[4];
  const float* kW2 = (const float*)d_in[5];
  const float* kb2 = (const float*)d_in[6];
  const float* qW1 = (const float*)d_in[7];
  const float* qg1 = (const float*)d_in[8];
  const float* qb1 = (const float*)d_in[9];
  const float* qW2 = (const float*)d_in[10];
  const float* qb2 = (const float*)d_in[11];
  const float* vW1 = (const float*)d_in[12];
  const float* vg1 = (const float*)d_in[13];
  const float* vb1 = (const float*)d_in[14];
  const float* vW2 = (const float*)d_in[15];
  const float* vb2 = (const float*)d_in[16];
  const float* aW1 = (const float*)d_in[17];
  const float* ag1 = (const float*)d_in[18];
  const float* ab1 = (const float*)d_in[19];
  const float* aW2 = (const float*)d_in[20];
  const float* ab2 = (const float*)d_in[21];
  const float* rW1 = (const float*)d_in[22];
  const float* rg1 = (const float*)d_in[23];
  const float* rb1 = (const float*)d_in[24];
  const float* rW2 = (const float*)d_in[25];
  const float* rg2 = (const float*)d_in[26];
  const float* rb2 = (const float*)d_in[27];
  const float* rW3 = (const float*)d_in[28];
  const float* rb3 = (const float*)d_in[29];
  const float* gW1 = (const float*)d_in[30];
  const float* gg1 = (const float*)d_in[31];
  const float* gb1 = (const float*)d_in[32];
  const float* gW2 = (const float*)d_in[33];
  const float* gb2 = (const float*)d_in[34];

  const int N = in_sizes[0] / 128;
  float* out = (float*)d_out;

  prepack_kernel<<<40, 256, 0, stream>>>(kW1, vW1, rW1, kW2, vW2, rW2,
                                         qW1, qW2, aW1, aW2, rW3, gW1, gW2);

  const int grid = (N + ROWS_PER_BLOCK - 1) / ROWS_PER_BLOCK;
  approach_mfma_kernel<<<grid, TPB, 0, stream>>>(
      rep, par,
      kg1, kb1, kb2,
      qg1, qb1, qb2,
      vg1, vb1, vb2,
      ag1, ab1, ab2,
      rg1, rb1, rg2, rb2, rb3,
      gg1, gb1, gb2,
      out, N);
}

// Round 17
// 221.209 us; speedup vs baseline: 1.6059x; 1.1640x over previous
//
#include <hip/hip_runtime.h>
#include <math.h>

#define LN_EPS 1e-5f
#define TPB 512
#define ROWS_PER_BLOCK 128  // 8 waves x 16 rows; weights staged once in LDS

typedef _Float16 half8 __attribute__((ext_vector_type(8)));
typedef float f32x4 __attribute__((ext_vector_type(4)));
typedef unsigned uint4v __attribute__((ext_vector_type(4)));

// fragment table offsets (halves); 512 halves (64 lanes x 8) per fragment.
#define OFF_W1   0        // 48 frags: towers k,v,r x cb(4) x kb(4), centered
#define OFF_WP   24576    // 4: residual param rows 128..130 (centered), K-slot j<3 @ g==0
#define OFF_QW1  26624    // 1: qW1 centered, K-slot j<3 @ g==0
#define OFF_KW2  27136    // 4: cb2(2) x kb(2), phi64-permuted K
#define OFF_VW2  29184    // 4
#define OFF_RW2  31232    // 4, centered
#define OFF_QW2  33280    // 2: cb2(2), phi16-padded K
#define OFF_AW1  34304    // 2: cb(2), phi32, centered
#define OFF_AW2  35328    // 1: phi32
#define OFF_RW3  35840    // 1: phi32
#define OFF_GW1  36352    // 1: phi32, centered
#define OFF_GW2  36864    // 1: phi16-padded
#define WL_HALVES 37376

__device__ _Float16 g_wfrag[WL_HALVES];   // 73 KB packed table (prepacked each launch)

__device__ __forceinline__ f32x4 mfma16(half8 a, half8 b, f32x4 c) {
  return __builtin_amdgcn_mfma_f32_16x16x32_f16(a, b, c, 0, 0, 0);
}
__device__ __forceinline__ unsigned pkrtz(float a, float b) {
  return __builtin_bit_cast(unsigned, __builtin_amdgcn_cvt_pkrtz(a, b));
}

// ---------------- prepack (byte-identical to validated R11/R14) ----------------

__device__ __forceinline__ void pack_l1(const float* __restrict__ W, int tower,
                                        int gtid, int gstride) {
  for (int idx = gtid; idx < 128 * 64; idx += gstride) {
    int k = idx >> 6, c = idx & 63;
    float m = 0.f;
    for (int c2 = 0; c2 < 64; ++c2) m += W[k * 64 + c2];
    float v = W[k * 64 + c] - m * (1.f / 64.f);
    int frag = tower * 16 + (c >> 4) * 4 + (k >> 5);
    int l = ((k >> 3) & 3) * 16 + (c & 15);
    g_wfrag[OFF_W1 + frag * 512 + l * 8 + (k & 7)] = (_Float16)v;
  }
}

__device__ __forceinline__ void pack_w2p(const float* __restrict__ W, int Kdim,
                                         int Ncols, int NB, int KB, int off,
                                         bool center, int gtid, int gstride) {
  int tot = NB * KB * 512;
  for (int idx = gtid; idx < tot; idx += gstride) {
    int j = idx & 7, l = (idx >> 3) & 63, frag = idx >> 9;
    int kb = frag % KB, cb2 = frag / KB;
    int g = l >> 4, lo = l & 15;
    int c2 = cb2 * 16 + lo;
    int ch = (kb * 2 + (j >> 2)) * 16 + g * 4 + (j & 3);
    float v = 0.f;
    if (c2 < Ncols && ch < Kdim) {
      v = W[ch * Ncols + c2];
      if (center) {
        float m = 0.f;
        for (int c = 0; c < Ncols; ++c) m += W[ch * Ncols + c];
        v -= m / (float)Ncols;
      }
    }
    g_wfrag[off + frag * 512 + l * 8 + j] = (_Float16)v;
  }
}

__device__ __forceinline__ void pack_pad16(const float* __restrict__ W, int Ncols,
                                           int NB, int off, int gtid, int gstride) {
  int tot = NB * 512;
  for (int idx = gtid; idx < tot; idx += gstride) {
    int j = idx & 7, l = (idx >> 3) & 63, cb2 = idx >> 9;
    int g = l >> 4, lo = l & 15;
    int c2 = cb2 * 16 + lo;
    float v = 0.f;
    if (j < 4 && c2 < Ncols) v = W[(g * 4 + j) * Ncols + c2];
    g_wfrag[off + cb2 * 512 + l * 8 + j] = (_Float16)v;
  }
}

__global__ void prepack_kernel(const float* kW1, const float* vW1, const float* rW1,
                               const float* kW2, const float* vW2, const float* rW2,
                               const float* qW1, const float* qW2, const float* aW1,
                               const float* aW2, const float* rW3, const float* gW1,
                               const float* gW2) {
  int gtid = blockIdx.x * blockDim.x + threadIdx.x;
  int gstride = gridDim.x * blockDim.x;
  pack_l1(kW1, 0, gtid, gstride);
  pack_l1(vW1, 1, gtid, gstride);
  pack_l1(rW1, 2, gtid, gstride);            // rows 0..127
  pack_w2p(kW2, 64, 32, 2, 2, OFF_KW2, false, gtid, gstride);
  pack_w2p(vW2, 64, 32, 2, 2, OFF_VW2, false, gtid, gstride);
  pack_w2p(rW2, 64, 32, 2, 2, OFF_RW2, true, gtid, gstride);
  pack_w2p(aW1, 32, 32, 2, 1, OFF_AW1, true, gtid, gstride);
  pack_w2p(aW2, 32, 16, 1, 1, OFF_AW2, false, gtid, gstride);
  pack_w2p(rW3, 32, 16, 1, 1, OFF_RW3, false, gtid, gstride);
  pack_w2p(gW1, 32, 16, 1, 1, OFF_GW1, true, gtid, gstride);
  pack_pad16(qW2, 32, 2, OFF_QW2, gtid, gstride);
  pack_pad16(gW2, 3, 1, OFF_GW2, gtid, gstride);
  // residual param frags: A[c = cb*16+lo, k=j (g==0, j<3)] = centered rW1 rows 128..130
  for (int idx = gtid; idx < 4 * 512; idx += gstride) {
    int j = idx & 7, l = (idx >> 3) & 63, cb = idx >> 9;
    int g = l >> 4, lo = l & 15;
    float v = 0.f;
    if (g == 0 && j < 3) {
      int k = 128 + j;
      float m = 0.f;
      for (int c = 0; c < 64; ++c) m += rW1[k * 64 + c];
      v = rW1[k * 64 + cb * 16 + lo] - m * (1.f / 64.f);
    }
    g_wfrag[OFF_WP + cb * 512 + l * 8 + j] = (_Float16)v;
  }
  // qW1 frag: A[c = lo, k=j (g==0, j<3)] = centered qW1
  for (int idx = gtid; idx < 512; idx += gstride) {
    int j = idx & 7, l = idx >> 3;
    int g = l >> 4, lo = l & 15;
    float v = 0.f;
    if (g == 0 && j < 3) {
      float m = 0.f;
      for (int c = 0; c < 16; ++c) m += qW1[j * 16 + c];
      v = qW1[j * 16 + lo] - m * (1.f / 16.f);
    }
    g_wfrag[OFF_QW1 + l * 8 + j] = (_Float16)v;
  }
}

// ------ main kernel: x-loads overlap LDS staging; weights in LDS; reg-resident LN ------

__global__ __launch_bounds__(TPB, 4)
void approach_mfma_kernel(
    const float* __restrict__ rep, const float* __restrict__ par,
    const float* __restrict__ kg1, const float* __restrict__ kb1, const float* __restrict__ kb2,
    const float* __restrict__ qg1, const float* __restrict__ qb1, const float* __restrict__ qb2,
    const float* __restrict__ vg1, const float* __restrict__ vb1, const float* __restrict__ vb2,
    const float* __restrict__ ag1, const float* __restrict__ ab1, const float* __restrict__ ab2,
    const float* __restrict__ rg1, const float* __restrict__ rb1,
    const float* __restrict__ rg2, const float* __restrict__ rb2, const float* __restrict__ rb3,
    const float* __restrict__ gg1, const float* __restrict__ gb1, const float* __restrict__ gb2,
    float* __restrict__ out, int N)
{
  __shared__ __align__(16) _Float16 wl[WL_HALVES];   // 73 KB -> 2 blocks/CU

  const int tid = threadIdx.x;
  const int wave = tid >> 6, lane = tid & 63;
  const int lo = lane & 15;   // row index (B col / D col)
  const int g = lane >> 4;    // k-group / D-row group
  const long long row0 = (long long)blockIdx.x * ROWS_PER_BLOCK + wave * 16;
  const bool active = (row0 + 16 <= N);

  // ---- issue x / param HBM loads FIRST (latency overlaps the LDS staging below);
  //      converted to f16 immediately -> no extra live registers vs R14.
  half8 xa[4], xp;
  if (active) {
    const float* xr = rep + (size_t)(row0 + lo) * 128 + g * 8;
#pragma unroll
    for (int kb = 0; kb < 4; ++kb) {
      f32x4 u0 = *reinterpret_cast<const f32x4*>(xr + kb * 32);
      f32x4 u1 = *reinterpret_cast<const f32x4*>(xr + kb * 32 + 4);
      uint4v u;
      u[0] = pkrtz(u0[0], u0[1]); u[1] = pkrtz(u0[2], u0[3]);
      u[2] = pkrtz(u1[0], u1[1]); u[3] = pkrtz(u1[2], u1[3]);
      xa[kb] = __builtin_bit_cast(half8, u);
    }
    const float* pr = par + (size_t)(row0 + lo) * 3;
    unsigned w0 = pkrtz(pr[0], pr[1]), w1 = pkrtz(pr[2], 0.f);
    uint4v u;
    u[0] = (g == 0) ? w0 : 0u; u[1] = (g == 0) ? w1 : 0u; u[2] = 0u; u[3] = 0u;
    xp = __builtin_bit_cast(half8, u);
  }

  // ---- stage the fragment table (once per block) — overlaps the x-load latency
  for (int i = tid * 8; i < WL_HALVES; i += TPB * 8)
    *reinterpret_cast<half8*>(&wl[i]) =
        *reinterpret_cast<const half8*>(&g_wfrag[i]);
  __syncthreads();

  if (!active) return;

  auto ldf = [&](int off, int frag) -> half8 {
    return *reinterpret_cast<const half8*>(&wl[off + frag * 512 + lane * 8]);
  };
  const f32x4 z4 = {0.f, 0.f, 0.f, 0.f};

  // ---- layer-1: h^T = W1^T x^T for k,v,r (+param tail) + q
  f32x4 aK[4], aV[4], aR[4];
#pragma unroll
  for (int cb = 0; cb < 4; ++cb) { aK[cb] = z4; aV[cb] = z4; aR[cb] = z4; }
#pragma unroll
  for (int cb = 0; cb < 4; ++cb)
#pragma unroll
    for (int kb = 0; kb < 4; ++kb) {
      aK[cb] = mfma16(ldf(OFF_W1, cb * 4 + kb), xa[kb], aK[cb]);
      aV[cb] = mfma16(ldf(OFF_W1, 16 + cb * 4 + kb), xa[kb], aV[cb]);
      aR[cb] = mfma16(ldf(OFF_W1, 32 + cb * 4 + kb), xa[kb], aR[cb]);
    }
#pragma unroll
  for (int cb = 0; cb < 4; ++cb) aR[cb] = mfma16(ldf(OFF_WP, cb), xp, aR[cb]);
  f32x4 aq = mfma16(ldf(OFF_QW1, 0), xp, z4);

  // LN64: mean-free rms-norm + affine + relu -> two phi64 B-frags
  auto ln64 = [&](const f32x4* a, const float* __restrict__ g1,
                  const float* __restrict__ b1, half8& b0, half8& b1o) {
    float t0 = 0.f, t1 = 0.f, t2 = 0.f, t3 = 0.f;
#pragma unroll
    for (int r = 0; r < 4; ++r) {
      t0 = fmaf(a[0][r], a[0][r], t0); t1 = fmaf(a[1][r], a[1][r], t1);
      t2 = fmaf(a[2][r], a[2][r], t2); t3 = fmaf(a[3][r], a[3][r], t3);
    }
    float ssq = (t0 + t1) + (t2 + t3);
    ssq += __shfl_xor(ssq, 16);
    ssq += __shfl_xor(ssq, 32);
    float rstd = rsqrtf(ssq * (1.f / 64.f) + LN_EPS);
    float h[4][4];
#pragma unroll
    for (int cb = 0; cb < 4; ++cb) {
      f32x4 gv = *reinterpret_cast<const f32x4*>(g1 + cb * 16 + g * 4);
      f32x4 bv = *reinterpret_cast<const f32x4*>(b1 + cb * 16 + g * 4);
#pragma unroll
      for (int r = 0; r < 4; ++r)
        h[cb][r] = fmaxf(fmaf(a[cb][r] * rstd, gv[r], bv[r]), 0.f);
    }
    uint4v u0, u1;
    u0[0] = pkrtz(h[0][0], h[0][1]); u0[1] = pkrtz(h[0][2], h[0][3]);
    u0[2] = pkrtz(h[1][0], h[1][1]); u0[3] = pkrtz(h[1][2], h[1][3]);
    u1[0] = pkrtz(h[2][0], h[2][1]); u1[1] = pkrtz(h[2][2], h[2][3]);
    u1[2] = pkrtz(h[3][0], h[3][1]); u1[3] = pkrtz(h[3][2], h[3][3]);
    b0 = __builtin_bit_cast(half8, u0);
    b1o = __builtin_bit_cast(half8, u1);
  };
  auto ln32 = [&](const f32x4* a, const float* __restrict__ g1,
                  const float* __restrict__ b1) -> half8 {
    float t0 = 0.f, t1 = 0.f;
#pragma unroll
    for (int r = 0; r < 4; ++r) {
      t0 = fmaf(a[0][r], a[0][r], t0); t1 = fmaf(a[1][r], a[1][r], t1);
    }
    float ssq = t0 + t1;
    ssq += __shfl_xor(ssq, 16);
    ssq += __shfl_xor(ssq, 32);
    float rstd = rsqrtf(ssq * (1.f / 32.f) + LN_EPS);
    float h[2][4];
#pragma unroll
    for (int cb = 0; cb < 2; ++cb) {
      f32x4 gv = *reinterpret_cast<const f32x4*>(g1 + cb * 16 + g * 4);
      f32x4 bv = *reinterpret_cast<const f32x4*>(b1 + cb * 16 + g * 4);
#pragma unroll
      for (int r = 0; r < 4; ++r)
        h[cb][r] = fmaxf(fmaf(a[cb][r] * rstd, gv[r], bv[r]), 0.f);
    }
    uint4v u;
    u[0] = pkrtz(h[0][0], h[0][1]); u[1] = pkrtz(h[0][2], h[0][3]);
    u[2] = pkrtz(h[1][0], h[1][1]); u[3] = pkrtz(h[1][2], h[1][3]);
    return __builtin_bit_cast(half8, u);
  };
  auto ln16 = [&](f32x4 a, const float* __restrict__ g1,
                  const float* __restrict__ b1) -> half8 {
    float ssq = 0.f;
#pragma unroll
    for (int r = 0; r < 4; ++r) ssq = fmaf(a[r], a[r], ssq);
    ssq += __shfl_xor(ssq, 16);
    ssq += __shfl_xor(ssq, 32);
    float rstd = rsqrtf(ssq * (1.f / 16.f) + LN_EPS);
    f32x4 gv = *reinterpret_cast<const f32x4*>(g1 + g * 4);
    f32x4 bv = *reinterpret_cast<const f32x4*>(b1 + g * 4);
    float h[4];
#pragma unroll
    for (int r = 0; r < 4; ++r)
      h[r] = fmaxf(fmaf(a[r] * rstd, gv[r], bv[r]), 0.f);
    uint4v u;
    u[0] = pkrtz(h[0], h[1]); u[1] = pkrtz(h[2], h[3]); u[2] = 0u; u[3] = 0u;
    return __builtin_bit_cast(half8, u);
  };

  // ---- key tower layer-2
  f32x4 kk[2], vv[2], qq[2], r16v, a16v;
  {
    half8 b0, b1;
    ln64(aK, kg1, kb1, b0, b1);
#pragma unroll
    for (int cb2 = 0; cb2 < 2; ++cb2) {
      f32x4 o = mfma16(ldf(OFF_KW2, cb2 * 2 + 1), b1,
                       mfma16(ldf(OFF_KW2, cb2 * 2), b0, z4));
      f32x4 bb = *reinterpret_cast<const f32x4*>(kb2 + cb2 * 16 + g * 4);
#pragma unroll
      for (int r = 0; r < 4; ++r) o[r] += bb[r];
      kk[cb2] = o;
    }
  }
  // ---- value tower layer-2
  {
    half8 b0, b1;
    ln64(aV, vg1, vb1, b0, b1);
#pragma unroll
    for (int cb2 = 0; cb2 < 2; ++cb2) {
      f32x4 o = mfma16(ldf(OFF_VW2, cb2 * 2 + 1), b1,
                       mfma16(ldf(OFF_VW2, cb2 * 2), b0, z4));
      f32x4 bb = *reinterpret_cast<const f32x4*>(vb2 + cb2 * 16 + g * 4);
#pragma unroll
      for (int r = 0; r < 4; ++r) o[r] += bb[r];
      vv[cb2] = o;
    }
  }
  // ---- residual tower layers 2-3
  {
    half8 b0, b1;
    ln64(aR, rg1, rb1, b0, b1);
    f32x4 r32[2];
#pragma unroll
    for (int cb = 0; cb < 2; ++cb)
      r32[cb] = mfma16(ldf(OFF_RW2, cb * 2 + 1), b1,
                       mfma16(ldf(OFF_RW2, cb * 2), b0, z4));
    half8 b32 = ln32(r32, rg2, rb2);
    f32x4 o = mfma16(ldf(OFF_RW3, 0), b32, z4);
    f32x4 bb = *reinterpret_cast<const f32x4*>(rb3 + g * 4);
#pragma unroll
    for (int r = 0; r < 4; ++r) o[r] += bb[r];
    r16v = o;
  }
  // ---- query tower layer-2
  {
    half8 bq = ln16(aq, qg1, qb1);
#pragma unroll
    for (int cb2 = 0; cb2 < 2; ++cb2) {
      f32x4 o = mfma16(ldf(OFF_QW2, cb2), bq, z4);
      f32x4 bb = *reinterpret_cast<const f32x4*>(qb2 + cb2 * 16 + g * 4);
#pragma unroll
      for (int r = 0; r < 4; ++r) o[r] += bb[r];
      qq[cb2] = o;
    }
  }
  // ---- attention: softmax(q*k)*v (raw exp; proven R8-R16)
  {
    float e[2][4];
    float s0 = 0.f, s1 = 0.f;
#pragma unroll
    for (int r = 0; r < 4; ++r) {
      e[0][r] = __expf(qq[0][r] * kk[0][r]);
      e[1][r] = __expf(qq[1][r] * kk[1][r]);
      s0 += e[0][r]; s1 += e[1][r];
    }
    float sm = s0 + s1;
    sm += __shfl_xor(sm, 16);
    sm += __shfl_xor(sm, 32);
    float inv = 1.f / sm;
    float at[2][4];
#pragma unroll
    for (int cb = 0; cb < 2; ++cb)
#pragma unroll
      for (int r = 0; r < 4; ++r) at[cb][r] = e[cb][r] * inv * vv[cb][r];
    uint4v ua;
    ua[0] = pkrtz(at[0][0], at[0][1]); ua[1] = pkrtz(at[0][2], at[0][3]);
    ua[2] = pkrtz(at[1][0], at[1][1]); ua[3] = pkrtz(at[1][2], at[1][3]);
    half8 ba = __builtin_bit_cast(half8, ua);
    f32x4 h32[2];
#pragma unroll
    for (int cb = 0; cb < 2; ++cb) h32[cb] = mfma16(ldf(OFF_AW1, cb), ba, z4);
    half8 bh = ln32(h32, ag1, ab1);
    f32x4 o = mfma16(ldf(OFF_AW2, 0), bh, z4);
    f32x4 bb = *reinterpret_cast<const f32x4*>(ab2 + g * 4);
#pragma unroll
    for (int r = 0; r < 4; ++r) o[r] += bb[r];
    a16v = o;
  }
  // ---- get_approach tower: concat(att [j<4], res [j>=4]) -> gW1 -> LN -> gW2
  {
    uint4v uf;
    uf[0] = pkrtz(a16v[0], a16v[1]); uf[1] = pkrtz(a16v[2], a16v[3]);
    uf[2] = pkrtz(r16v[0], r16v[1]); uf[3] = pkrtz(r16v[2], r16v[3]);
    half8 bf = __builtin_bit_cast(half8, uf);
    f32x4 f1 = mfma16(ldf(OFF_GW1, 0), bf, z4);
    half8 bf1 = ln16(f1, gg1, gb1);
    f32x4 og = mfma16(ldf(OFF_GW2, 0), bf1, z4);
    if (g == 0) {
      float* op = out + (size_t)(row0 + lo) * 3;
#pragma unroll
      for (int r = 0; r < 3; ++r) op[r] = og[r] + gb2[r];
    }
  }
}

// ---------------- launch ----------------

extern "C" void kernel_launch(void* const* d_in, const int* in_sizes, int n_in,
                              void* d_out, int out_size, void* d_ws, size_t ws_size,
                              hipStream_t stream) {
  const float* rep = (const float*)d_in[0];
  const float* par = (const float*)d_in[1];
  const float* kW1 = (const float*)d_in[2];
  const float* kg1 = (const float*)d_in[3];
  const float* kb1 = (const float*)d_in[4];
  const float* kW2 = (const float*)d_in[5];
  const float* kb2 = (const float*)d_in[6];
  const float* qW1 = (const float*)d_in[7];
  const float* qg1 = (const float*)d_in[8];
  const float* qb1 = (const float*)d_in[9];
  const float* qW2 = (const float*)d_in[10];
  const float* qb2 = (const float*)d_in[11];
  const float* vW1 = (const float*)d_in[12];
  const float* vg1 = (const float*)d_in[13];
  const float* vb1 = (const float*)d_in[14];
  const float* vW2 = (const float*)d_in[15];
  const float* vb2 = (const float*)d_in[16];
  const float* aW1 = (const float*)d_in[17];
  const float* ag1 = (const float*)d_in[18];
  const float* ab1 = (const float*)d_in[19];
  const float* aW2 = (const float*)d_in[20];
  const float* ab2 = (const float*)d_in[21];
  const float* rW1 = (const float*)d_in[22];
  const float* rg1 = (const float*)d_in[23];
  const float* rb1 = (const float*)d_in[24];
  const float* rW2 = (const float*)d_in[25];
  const float* rg2 = (const float*)d_in[26];
  const float* rb2 = (const float*)d_in[27];
  const float* rW3 = (const float*)d_in[28];
  const float* rb3 = (const float*)d_in[29];
  const float* gW1 = (const float*)d_in[30];
  const float* gg1 = (const float*)d_in[31];
  const float* gb1 = (const float*)d_in[32];
  const float* gW2 = (const float*)d_in[33];
  const float* gb2 = (const float*)d_in[34];

  const int N = in_sizes[0] / 128;
  float* out = (float*)d_out;

  prepack_kernel<<<40, 256, 0, stream>>>(kW1, vW1, rW1, kW2, vW2, rW2,
                                         qW1, qW2, aW1, aW2, rW3, gW1, gW2);

  const int grid = (N + ROWS_PER_BLOCK - 1) / ROWS_PER_BLOCK;
  approach_mfma_kernel<<<grid, TPB, 0, stream>>>(
      rep, par,
      kg1, kb1, kb2,
      qg1, qb1, qb2,
      vg1, vb1, vb2,
      ag1, ab1, ab2,
      rg1, rb1, rg2, rb2, rb3,
      gg1, gb1, gb2,
      out, N);
}